// Round 15
// baseline (199.662 us; speedup 1.0000x reference)
//
#include <hip/hip_runtime.h>
#include <stdint.h>

#define NROWS 4096
#define DIM   128
#define KB    8
#define NS    7            // K-1 negatives per anchor
#define TCH   16           // candidate chunks (256 cands each)
#define NPAIR 2048
#define HALF_CNT 58720256u // (4096*7*4096)/2

typedef __bf16 v8bf __attribute__((ext_vector_type(8)));
typedef float  v4f  __attribute__((ext_vector_type(4)));

// forced single-instruction rotate (v_alignbit_b32)
__device__ __forceinline__ uint32_t rotl32(uint32_t x, int r) {
    return __builtin_amdgcn_alignbit(x, x, 32 - r);
}

// JAX threefry2x32, key = [0, 42], 20 rounds. (c0,c1)=(L, L+HALF_CNT):
// o0 = bits for flat index L, o1 = bits for flat index L+HALF_CNT.
__device__ __forceinline__ void threefry2x32(uint32_t c0, uint32_t c1,
                                             uint32_t& o0, uint32_t& o1) {
    const uint32_t ks0 = 0u;
    const uint32_t ks1 = 42u;
    const uint32_t ks2 = 0x1BD11BDAu ^ ks0 ^ ks1;
    uint32_t x0 = c0 + ks0;
    uint32_t x1 = c1 + ks1;
#define TF_R(r) { x0 += x1; x1 = rotl32(x1, r); x1 ^= x0; }
    TF_R(13) TF_R(15) TF_R(26) TF_R(6)
    x0 += ks1; x1 += ks2 + 1u;
    TF_R(17) TF_R(29) TF_R(16) TF_R(24)
    x0 += ks2; x1 += ks0 + 2u;
    TF_R(13) TF_R(15) TF_R(26) TF_R(6)
    x0 += ks0; x1 += ks1 + 3u;
    TF_R(17) TF_R(29) TF_R(16) TF_R(24)
    x0 += ks1; x1 += ks2 + 4u;
    TF_R(13) TF_R(15) TF_R(26) TF_R(6)
    x0 += ks2; x1 += ks0 + 5u;
#undef TF_R
    o0 = x0; o1 = x1;
}

// gumbel = -ln(-ln(u)) (used only by the never-fires kfixup)
__device__ __forceinline__ float gumbel_of(uint32_t b) {
    float f = __uint_as_float((b >> 9) | 0x3f800000u) - 1.0f;   // [0,1)
    float u = f + 1.17549435e-38f;
    float l1 = __log2f(u);
    float inner = -0.69314718055994531f * l1;
    float l2 = __log2f(inner);
    return -0.69314718055994531f * l2;
}

// ---------------- kernel 1: normalize -> bf16 plane + sq ------------------
__global__ void knorm(const float* __restrict__ x, __bf16* __restrict__ xb,
                      float* __restrict__ sqv) {
    const int i = blockIdx.x;
    const int t = threadIdx.x;  // 64 threads, 2 elems each
    float2 v = ((const float2*)(x + (size_t)i * DIM))[t];
    float s = v.x * v.x + v.y * v.y;
#pragma unroll
    for (int m = 32; m > 0; m >>= 1) s += __shfl_xor(s, m, 64);
    float norm = sqrtf(s) + 1e-5f;
    float ox = v.x / norm, oy = v.y / norm;
    union { __bf16 b[2]; uint32_t u; } ph;
    ph.b[0] = (__bf16)ox; ph.b[1] = (__bf16)oy;
    ((uint32_t*)xb)[i * 64 + t] = ph.u;
    float s2 = ox * ox + oy * oy;
#pragma unroll
    for (int m = 32; m > 0; m >>= 1) s2 += __shfl_xor(s2, m, 64);
    if (t == 0) sqv[i] = s2;
}

// ---------------- kernel 2a: MFMA dists -> compacted lists (negwinv) ------
// 128-thread blocks (2 chunks) for more blocks/CU -> latency hiding.
__global__ __launch_bounds__(128, 8) void kdist(
        const __bf16* __restrict__ xb, const float* __restrict__ sqv,
        int* __restrict__ cnt, unsigned short* __restrict__ t16,
        float2* __restrict__ nwp) {
    const int lane  = threadIdx.x & 63;
    const int chunk = (blockIdx.x << 1) + (threadIdx.x >> 6);   // 0..15
    const int grp   = blockIdx.y;   // 0..255
    const int rlo = lane & 15;
    const int khi = lane >> 4;
    const unsigned int below = (1u << rlo) - 1u;

    const int afr = grp * 8 + (rlo >> 1) + ((rlo & 1) << 11);
    v8bf ah[4];
#pragma unroll
    for (int ks = 0; ks < 4; ++ks)
        ah[ks] = *(const v8bf*)(xb + (size_t)afr * DIM + ks * 32 + khi * 8);

    const int base = grp * 8 + khi * 2;   // pairA = base, pairB = base+1
    float sqA[4];
    sqA[0] = sqv[base];
    sqA[1] = sqv[base + 2048];
    sqA[2] = sqv[base + 1];
    sqA[3] = sqv[base + 2049];

    const int rbA = ((base)     * 16 + chunk) << 8;
    const int rbB = ((base + 1) * 16 + chunk) << 8;
    unsigned int cA = 0, cB = 0;          // uniform within 16-group

    const int tcol0 = chunk * 256 + rlo;

    v8bf bhn[4];
    float sqn;
    {
        const size_t boff = (size_t)tcol0 * DIM + khi * 8;
#pragma unroll
        for (int ks = 0; ks < 4; ++ks) bhn[ks] = *(const v8bf*)(xb + boff + ks * 32);
        sqn = sqv[tcol0];
    }

#pragma unroll 1
    for (int cg = 0; cg < 16; ++cg) {
        v8bf bhc[4];
#pragma unroll
        for (int ks = 0; ks < 4; ++ks) bhc[ks] = bhn[ks];
        const float sqB = sqn;
        const int tcol = tcol0 + cg * 16;

        if (cg < 15) {
            const size_t boff = (size_t)(tcol + 16) * DIM + khi * 8;
#pragma unroll
            for (int ks = 0; ks < 4; ++ks) bhn[ks] = *(const v8bf*)(xb + boff + ks * 32);
            sqn = sqv[tcol + 16];
        }

        v4f acc = {0.f, 0.f, 0.f, 0.f};
#pragma unroll
        for (int ks = 0; ks < 4; ++ks)
            acc = __builtin_amdgcn_mfma_f32_16x16x32_bf16(ah[ks], bhc[ks], acc, 0, 0, 0);

        const int tBlk = tcol >> 3;
        const bool bd0 = (tBlk != grp);
        const bool bd1 = (tBlk != grp + 256);

        float nw[4];
        bool  ic[4];
#pragma unroll
        for (int q = 0; q < 4; ++q) {
            float d2  = fmaf(-2.0f, acc[q], sqA[q] + sqB);
            float l1  = __log2f(d2);
            float t2  = fmaf(-0.25f, d2, 1.0f);
            float l2  = __log2f(t2);
            // negwinv = -exp(lg)^-1 : lg_nat = -63 ln(d2) - 62.5 ln(1-d2/4)
            float wiv = exp2f(fmaf(63.0f, l1, 62.5f * l2));
            bool incl = (d2 < 1.96f) && ((q & 1) ? bd1 : bd0);
            ic[q] = incl;
            nw[q] = incl ? -wiv : -INFINITY;
        }

        const bool uA = ic[0] | ic[1];
        const bool uB = ic[2] | ic[3];
        unsigned long long ballA = __ballot(uA);
        unsigned long long ballB = __ballot(uB);
        unsigned int subA = (unsigned int)((ballA >> (khi * 16)) & 0xFFFFull);
        unsigned int subB = (unsigned int)((ballB >> (khi * 16)) & 0xFFFFull);
        if (uA) {
            int slot = rbA + (int)cA + __popc(subA & below);
            t16[slot] = (unsigned short)tcol;
            nwp[slot] = make_float2(nw[0], nw[1]);
        }
        if (uB) {
            int slot = rbB + (int)cB + __popc(subB & below);
            t16[slot] = (unsigned short)tcol;
            nwp[slot] = make_float2(nw[2], nw[3]);
        }
        cA += (unsigned int)__popc(subA);
        cB += (unsigned int)__popc(subB);
    }

    if (rlo == 0) {
        cnt[base * 16 + chunk]       = (int)cA;
        cnt[(base + 1) * 16 + chunk] = (int)cB;
    }
}

// ---------------- kernel 2b: argmin E/w, flattened 4-region scan ----------
// Block = pair (2048 x 256). Wave w owns regions 4w..4w+3, FLATTENED into
// one index space [0, n0+n1+n2+n3) so ragged per-region tails don't idle
// lanes (region/offset recovered with 3 compares; counts are wave-uniform).
// Each lane owns one entry and runs the 7 sample-chains in a fully-
// unrolled register loop. Block LDS-reduce writes nidx directly.
// u64 key (key_bits<<32)|t == (key smaller)||(equal && t smaller)
// == reference argmax first-index; order-independent.
__global__ __launch_bounds__(256, 4) void kgum(
        const int* __restrict__ cnt, const unsigned short* __restrict__ t16,
        const float2* __restrict__ nwp, int* __restrict__ nidx) {
    const int p    = blockIdx.x;              // pair
    const int wid  = threadIdx.x >> 6;        // 0..3
    const int lane = threadIdx.x & 63;
    const uint32_t pb0 = ((uint32_t)p * 7u) << 12;

    const int rid0 = p * 16 + wid * 4;
    const int n0 = cnt[rid0];
    const int n1 = cnt[rid0 + 1];
    const int n2 = cnt[rid0 + 2];
    const int n3 = cnt[rid0 + 3];
    const int s1 = n0 + n1;
    const int s2 = s1 + n2;
    const int tot = s2 + n3;
    const int rb0 = rid0 << 8;

    unsigned long long bA[NS], bB[NS];
#pragma unroll
    for (int j = 0; j < NS; ++j) { bA[j] = ~0ull; bB[j] = ~0ull; }

#pragma unroll 1
    for (int g = lane; g < tot; g += 64) {
        int r, off;
        if (g < n0)      { r = 0; off = g; }
        else if (g < s1) { r = 1; off = g - n0; }
        else if (g < s2) { r = 2; off = g - s1; }
        else             { r = 3; off = g - s2; }
        const int idx = rb0 + (r << 8) + off;
        const uint32_t t = t16[idx];
        const float2 nw  = nwp[idx];
#pragma unroll
        for (int j = 0; j < NS; ++j) {
            const uint32_t L = pb0 + ((uint32_t)j << 12) + t;
            uint32_t o0, o1;
            threefry2x32(L, L + HALF_CNT, o0, o1);
            float fA = __uint_as_float((o0 >> 9) | 0x3f800000u) - 1.0f;
            float fB = __uint_as_float((o1 >> 9) | 0x3f800000u) - 1.0f;
            float kA = __log2f(fA + 1.17549435e-38f) * nw.x;
            float kB = __log2f(fB + 1.17549435e-38f) * nw.y;
            unsigned long long pA =
                ((unsigned long long)__float_as_uint(kA) << 32) | t;
            unsigned long long pB =
                ((unsigned long long)__float_as_uint(kB) << 32) | t;
            bA[j] = pA < bA[j] ? pA : bA[j];
            bB[j] = pB < bB[j] ? pB : bB[j];
        }
    }

    // reduce across 64 lanes: u64 min per j
#pragma unroll
    for (int j = 0; j < NS; ++j) {
#pragma unroll
        for (int m = 1; m < 64; m <<= 1) {
            unsigned long long vA = __shfl_xor(bA[j], m, 64);
            unsigned long long vB = __shfl_xor(bB[j], m, 64);
            bA[j] = vA < bA[j] ? vA : bA[j];
            bB[j] = vB < bB[j] ? vB : bB[j];
        }
    }

    __shared__ unsigned long long sA[4][NS], sB[4][NS];
    if (lane == 0) {
#pragma unroll
        for (int j = 0; j < NS; ++j) { sA[wid][j] = bA[j]; sB[wid][j] = bB[j]; }
    }
    __syncthreads();
    if (threadIdx.x < 2 * NS) {
        const int r = threadIdx.x / NS, j = threadIdx.x - r * NS;
        unsigned long long v = r ? sB[0][j] : sA[0][j];
#pragma unroll
        for (int w = 1; w < 4; ++w) {
            unsigned long long v2 = r ? sB[w][j] : sA[w][j];
            v = v2 < v ? v2 : v;
        }
        uint32_t kb = (uint32_t)(v >> 32);
        nidx[(p + r * 2048) * NS + j] = (kb >= 0x7F800000u) ? -1
                                                            : (int)(v & 0xFFFFu);
    }
}

// ---------------- fallback (small ws): fused sample, min-key partials -----
__global__ __launch_bounds__(256, 2) void ksample(
        const __bf16* __restrict__ xb, const float* __restrict__ sqv,
        float* __restrict__ pV, int* __restrict__ pI) {
    const int lane  = threadIdx.x & 63;
    const int chunk = (blockIdx.x << 2) + (threadIdx.x >> 6);
    const int grp   = blockIdx.y;
    const int rlo = lane & 15;
    const int khi = lane >> 4;

    const int afr = grp * 8 + (rlo >> 1) + ((rlo & 1) << 11);
    v8bf ah[4];
#pragma unroll
    for (int ks = 0; ks < 4; ++ks)
        ah[ks] = *(const v8bf*)(xb + (size_t)afr * DIM + ks * 32 + khi * 8);
    const int base = grp * 8 + khi * 2;
    float sqA[4];
    sqA[0] = sqv[base];
    sqA[1] = sqv[base + 2048];
    sqA[2] = sqv[base + 1];
    sqA[3] = sqv[base + 2049];
    const uint32_t P0 = (uint32_t)base;
    const uint32_t P1 = (uint32_t)(base + 1);

    float    bestV[4][NS];
    uint32_t bestP[4];
#pragma unroll
    for (int q = 0; q < 4; ++q) {
        bestP[q] = 0u;
#pragma unroll
        for (int j = 0; j < NS; ++j) bestV[q][j] = INFINITY;
    }
    const int tcol0 = chunk * 256 + rlo;

    v8bf bhn[4];
    float sqn;
    {
        const size_t boff = (size_t)tcol0 * DIM + khi * 8;
#pragma unroll
        for (int ks = 0; ks < 4; ++ks) bhn[ks] = *(const v8bf*)(xb + boff + ks * 32);
        sqn = sqv[tcol0];
    }

#pragma unroll 1
    for (int cg = 0; cg < 16; ++cg) {
        v8bf bhc[4];
#pragma unroll
        for (int ks = 0; ks < 4; ++ks) bhc[ks] = bhn[ks];
        const float sqB = sqn;
        const int tcol = tcol0 + cg * 16;
        if (cg < 15) {
            const size_t boff = (size_t)(tcol + 16) * DIM + khi * 8;
#pragma unroll
            for (int ks = 0; ks < 4; ++ks) bhn[ks] = *(const v8bf*)(xb + boff + ks * 32);
            sqn = sqv[tcol + 16];
        }
        v4f acc = {0.f, 0.f, 0.f, 0.f};
#pragma unroll
        for (int ks = 0; ks < 4; ++ks)
            acc = __builtin_amdgcn_mfma_f32_16x16x32_bf16(ah[ks], bhc[ks], acc, 0, 0, 0);
        const int tBlk = tcol >> 3;
        const bool bd0 = (tBlk != grp);
        const bool bd1 = (tBlk != grp + 256);
        float nw[4];
#pragma unroll
        for (int q = 0; q < 4; ++q) {
            float d2  = fmaf(-2.0f, acc[q], sqA[q] + sqB);
            float l1  = __log2f(d2);
            float t2  = fmaf(-0.25f, d2, 1.0f);
            float l2  = __log2f(t2);
            float wiv = exp2f(fmaf(63.0f, l1, 62.5f * l2));
            bool incl = (d2 < 1.96f) && ((q & 1) ? bd1 : bd0);
            nw[q] = incl ? -wiv : -INFINITY;
        }
        const uint32_t tB = (uint32_t)tcol;
#pragma unroll
        for (int j = 0; j < NS; ++j) {
            uint32_t L0 = ((P0 * 7u + (uint32_t)j) << 12) + tB;
            uint32_t L1 = ((P1 * 7u + (uint32_t)j) << 12) + tB;
            uint32_t o0, o1, o2, o3;
            threefry2x32(L0, L0 + HALF_CNT, o0, o1);
            threefry2x32(L1, L1 + HALF_CNT, o2, o3);
            float vv[4];
            vv[0] = __log2f(__uint_as_float((o0 >> 9) | 0x3f800000u) - 1.0f + 1.17549435e-38f) * nw[0];
            vv[1] = __log2f(__uint_as_float((o1 >> 9) | 0x3f800000u) - 1.0f + 1.17549435e-38f) * nw[1];
            vv[2] = __log2f(__uint_as_float((o2 >> 9) | 0x3f800000u) - 1.0f + 1.17549435e-38f) * nw[2];
            vv[3] = __log2f(__uint_as_float((o3 >> 9) | 0x3f800000u) - 1.0f + 1.17549435e-38f) * nw[3];
            const uint32_t keep = ~(0xFu << (4 * j));
            const uint32_t put  = ((uint32_t)cg) << (4 * j);
#pragma unroll
            for (int q = 0; q < 4; ++q) {
                bool lt = vv[q] < bestV[q][j];
                uint32_t np = (bestP[q] & keep) | put;
                bestV[q][j] = lt ? vv[q] : bestV[q][j];
                bestP[q]    = lt ? np : bestP[q];
            }
        }
    }
#pragma unroll
    for (int q = 0; q < 4; ++q) {
        const int a = base + (q >> 1) + ((q & 1) << 11);
#pragma unroll
        for (int j = 0; j < NS; ++j) {
            float v = bestV[q][j];
            int idx = tcol0 + (int)((bestP[q] >> (4 * j)) & 0xFu) * 16;
#pragma unroll
            for (int m = 1; m < 16; m <<= 1) {
                float v2 = __shfl_xor(v, m, 16);
                int   i2 = __shfl_xor(idx, m, 16);
                if (v2 < v || (v2 == v && i2 < idx)) { v = v2; idx = i2; }
            }
            if (rlo == 0) {
                size_t s = ((size_t)a * NS + j) * TCH + chunk;
                pV[s] = v;
                pI[s] = idx;
            }
        }
    }
}

__global__ void kcombine(const float* __restrict__ pV, const int* __restrict__ pI,
                         int* __restrict__ nidx, int nc) {
    int s = blockIdx.x * 256 + threadIdx.x;
    if (s >= NROWS * NS) return;
    float bv = INFINITY;
    int bi = 0x7FFFFFFF;
    for (int c = 0; c < nc; ++c) {
        float v = pV[(size_t)s * nc + c];
        int idx = pI[(size_t)s * nc + c];
        if (v < bv || (v == bv && idx < bi)) { bv = v; bi = idx; }
    }
    nidx[s] = (bv == INFINITY) ? -1 : bi;
}

// ---------------- kernel 4: uniform fallback for invalid rows -------------
__global__ void kfixup(int* __restrict__ nidx) {
    const int i = blockIdx.x;
    if (nidx[(size_t)i * NS] >= 0) return;   // normal case: immediate exit
    const int lane = threadIdx.x;            // 64
    for (int j = 0; j < NS; ++j) {
        float bv = -INFINITY;
        int bi = 0x7FFFFFFF;
        for (int t = lane; t < NROWS; t += 64) {
            uint32_t o0, o1;
            float g;
            if (i < 2048) {
                uint32_t L = (((uint32_t)(i * NS + j)) << 12) + (uint32_t)t;
                threefry2x32(L, L + HALF_CNT, o0, o1);
                g = gumbel_of(o0);
            } else {
                uint32_t L = (((uint32_t)((i - 2048) * NS + j)) << 12) + (uint32_t)t;
                threefry2x32(L, L + HALF_CNT, o0, o1);
                g = gumbel_of(o1);
            }
            if (g > bv) { bv = g; bi = t; }
        }
#pragma unroll
        for (int m = 1; m < 64; m <<= 1) {
            float v2 = __shfl_xor(bv, m, 64);
            int   i2 = __shfl_xor(bi, m, 64);
            if (v2 > bv || (v2 == bv && i2 < bi)) { bv = v2; bi = i2; }
        }
        if (lane == 0) nidx[i * NS + j] = bi;
    }
}

// ---------------- kernel 5: triplet losses --------------------------------
__global__ void kloss(const float* __restrict__ x, const int* __restrict__ nidx,
                      float* __restrict__ loss) {
    int s = blockIdx.x * 256 + threadIdx.x;
    if (s >= NROWS * NS) return;
    int i = s / NS, j = s - i * NS;
    int r = i & (KB - 1), blk = i >> 3;
    int po = (j < r) ? j : j + 1;
    int p = blk * KB + po;
    int n = nidx[s] & (NROWS - 1);      // defensive clamp (no-op when correct)
    const float4* A  = (const float4*)(x + (size_t)i * DIM);
    const float4* P  = (const float4*)(x + (size_t)p * DIM);
    const float4* Ng = (const float4*)(x + (size_t)n * DIM);
    float sap = 0.0f, san = 0.0f;
#pragma unroll 8
    for (int k = 0; k < DIM / 4; ++k) {
        float4 a = A[k], pv = P[k], nv = Ng[k];
        float d;
        d = a.x - pv.x + 1e-6f; sap += d * d;
        d = a.y - pv.y + 1e-6f; sap += d * d;
        d = a.z - pv.z + 1e-6f; sap += d * d;
        d = a.w - pv.w + 1e-6f; sap += d * d;
        d = a.x - nv.x + 1e-6f; san += d * d;
        d = a.y - nv.y + 1e-6f; san += d * d;
        d = a.z - nv.z + 1e-6f; san += d * d;
        d = a.w - nv.w + 1e-6f; san += d * d;
    }
    loss[s] = fmaxf(sqrtf(sap) - sqrtf(san) + 1.0f, 0.0f);
}

// ---------------- kernel 6: mean ------------------------------------------
__global__ void kreduce(const float* __restrict__ loss, float* __restrict__ out) {
    __shared__ float part[4];
    const int tid = threadIdx.x;
    float sum = 0.0f;
    for (int s = tid; s < NROWS * NS; s += 256) sum += loss[s];
#pragma unroll
    for (int m = 32; m > 0; m >>= 1) sum += __shfl_xor(sum, m, 64);
    if ((tid & 63) == 0) part[tid >> 6] = sum;
    __syncthreads();
    if (tid == 0) out[0] = (part[0] + part[1] + part[2] + part[3]) / 28672.0f;
}

extern "C" void kernel_launch(void* const* d_in, const int* in_sizes, int n_in,
                              void* d_out, int out_size, void* d_ws, size_t ws_size,
                              hipStream_t stream) {
    const float* x = (const float*)d_in[0];
    float* out = (float*)d_out;

    uint8_t* w = (uint8_t*)d_ws;
    size_t off = 0;
    auto take = [&](size_t bytes) {
        void* p = w + off;
        off = (off + bytes + 255) & ~(size_t)255;
        return p;
    };
    __bf16* xb   = (__bf16*)take((size_t)NROWS * DIM * 2);
    float*  sqv  = (float*)take((size_t)NROWS * 4);
    int*    nidx = (int*)take((size_t)NROWS * NS * 4);
    float*  loss = (float*)take((size_t)NROWS * NS * 4);
    int*    cnt  = (int*)take((size_t)NPAIR * 16 * 4);   // per-(pair,chunk)
    const size_t prefix = off;
    const size_t t16_b = (size_t)NPAIR * 16 * 256 * 2;   // 16.8 MB
    const size_t nwp_b = (size_t)NPAIR * 16 * 256 * 8;   // 67.1 MB
    const size_t NEED_BIG = prefix + ((t16_b + 255) & ~(size_t)255)
                          + ((nwp_b + 255) & ~(size_t)255);

    knorm<<<NROWS, 64, 0, stream>>>(x, xb, sqv);

    if (ws_size >= NEED_BIG) {
        unsigned short* t16 = (unsigned short*)take(t16_b);
        float2*         nwp = (float2*)take(nwp_b);
        kdist<<<dim3(TCH / 2, 256), 128, 0, stream>>>(xb, sqv, cnt, t16, nwp);
        kgum<<<NPAIR, 256, 0, stream>>>(cnt, t16, nwp, nidx);
    } else {
        float* pV = (float*)take((size_t)NROWS * NS * TCH * 4);
        int*   pI = (int*)take((size_t)NROWS * NS * TCH * 4);
        ksample<<<dim3(TCH / 4, 256), 256, 0, stream>>>(xb, sqv, pV, pI);
        kcombine<<<(NROWS * NS + 255) / 256, 256, 0, stream>>>(pV, pI, nidx, TCH);
    }

    kfixup<<<NROWS, 64, 0, stream>>>(nidx);
    kloss<<<(NROWS * NS + 255) / 256, 256, 0, stream>>>(x, nidx, loss);
    kreduce<<<1, 256, 0, stream>>>(loss, out);
}

// Round 16
// 193.855 us; speedup vs baseline: 1.0300x; 1.0300x over previous
//
#include <hip/hip_runtime.h>
#include <stdint.h>

#define NROWS 4096
#define DIM   128
#define KB    8
#define NS    7            // K-1 negatives per anchor
#define TCH   16           // candidate chunks (256 cands each)
#define NPAIR 2048
#define HALF_CNT 58720256u // (4096*7*4096)/2

typedef __bf16 v8bf __attribute__((ext_vector_type(8)));
typedef float  v4f  __attribute__((ext_vector_type(4)));

// forced single-instruction rotate (v_alignbit_b32)
__device__ __forceinline__ uint32_t rotl32(uint32_t x, int r) {
    return __builtin_amdgcn_alignbit(x, x, 32 - r);
}

// JAX threefry2x32, key = [0, 42], 20 rounds. (c0,c1)=(L, L+HALF_CNT):
// o0 = bits for flat index L, o1 = bits for flat index L+HALF_CNT.
__device__ __forceinline__ void threefry2x32(uint32_t c0, uint32_t c1,
                                             uint32_t& o0, uint32_t& o1) {
    const uint32_t ks0 = 0u;
    const uint32_t ks1 = 42u;
    const uint32_t ks2 = 0x1BD11BDAu ^ ks0 ^ ks1;
    uint32_t x0 = c0 + ks0;
    uint32_t x1 = c1 + ks1;
#define TF_R(r) { x0 += x1; x1 = rotl32(x1, r); x1 ^= x0; }
    TF_R(13) TF_R(15) TF_R(26) TF_R(6)
    x0 += ks1; x1 += ks2 + 1u;
    TF_R(17) TF_R(29) TF_R(16) TF_R(24)
    x0 += ks2; x1 += ks0 + 2u;
    TF_R(13) TF_R(15) TF_R(26) TF_R(6)
    x0 += ks0; x1 += ks1 + 3u;
    TF_R(17) TF_R(29) TF_R(16) TF_R(24)
    x0 += ks1; x1 += ks2 + 4u;
    TF_R(13) TF_R(15) TF_R(26) TF_R(6)
    x0 += ks2; x1 += ks0 + 5u;
#undef TF_R
    o0 = x0; o1 = x1;
}

// gumbel = -ln(-ln(u)) (used only by the never-fires kfixup)
__device__ __forceinline__ float gumbel_of(uint32_t b) {
    float f = __uint_as_float((b >> 9) | 0x3f800000u) - 1.0f;   // [0,1)
    float u = f + 1.17549435e-38f;
    float l1 = __log2f(u);
    float inner = -0.69314718055994531f * l1;
    float l2 = __log2f(inner);
    return -0.69314718055994531f * l2;
}

// ---------------- kernel 1: normalize -> bf16 plane + sq ------------------
__global__ void knorm(const float* __restrict__ x, __bf16* __restrict__ xb,
                      float* __restrict__ sqv) {
    const int i = blockIdx.x;
    const int t = threadIdx.x;  // 64 threads, 2 elems each
    float2 v = ((const float2*)(x + (size_t)i * DIM))[t];
    float s = v.x * v.x + v.y * v.y;
#pragma unroll
    for (int m = 32; m > 0; m >>= 1) s += __shfl_xor(s, m, 64);
    float norm = sqrtf(s) + 1e-5f;
    float ox = v.x / norm, oy = v.y / norm;
    union { __bf16 b[2]; uint32_t u; } ph;
    ph.b[0] = (__bf16)ox; ph.b[1] = (__bf16)oy;
    ((uint32_t*)xb)[i * 64 + t] = ph.u;
    float s2 = ox * ox + oy * oy;
#pragma unroll
    for (int m = 32; m > 0; m >>= 1) s2 += __shfl_xor(s2, m, 64);
    if (t == 0) sqv[i] = s2;
}

// ---------------- kernel 2a: MFMA dists -> compacted lists (negwinv) ------
// (R14 config: 256-thread blocks, 4 chunks/block — measured best)
__global__ __launch_bounds__(256, 4) void kdist(
        const __bf16* __restrict__ xb, const float* __restrict__ sqv,
        int* __restrict__ cnt, unsigned short* __restrict__ t16,
        float2* __restrict__ nwp) {
    const int lane  = threadIdx.x & 63;
    const int chunk = (blockIdx.x << 2) + (threadIdx.x >> 6);   // 0..15
    const int grp   = blockIdx.y;   // 0..255
    const int rlo = lane & 15;
    const int khi = lane >> 4;
    const unsigned int below = (1u << rlo) - 1u;

    const int afr = grp * 8 + (rlo >> 1) + ((rlo & 1) << 11);
    v8bf ah[4];
#pragma unroll
    for (int ks = 0; ks < 4; ++ks)
        ah[ks] = *(const v8bf*)(xb + (size_t)afr * DIM + ks * 32 + khi * 8);

    const int base = grp * 8 + khi * 2;   // pairA = base, pairB = base+1
    float sqA[4];
    sqA[0] = sqv[base];
    sqA[1] = sqv[base + 2048];
    sqA[2] = sqv[base + 1];
    sqA[3] = sqv[base + 2049];

    const int rbA = ((base)     * 16 + chunk) << 8;
    const int rbB = ((base + 1) * 16 + chunk) << 8;
    unsigned int cA = 0, cB = 0;          // uniform within 16-group

    const int tcol0 = chunk * 256 + rlo;

    v8bf bhn[4];
    float sqn;
    {
        const size_t boff = (size_t)tcol0 * DIM + khi * 8;
#pragma unroll
        for (int ks = 0; ks < 4; ++ks) bhn[ks] = *(const v8bf*)(xb + boff + ks * 32);
        sqn = sqv[tcol0];
    }

#pragma unroll 1
    for (int cg = 0; cg < 16; ++cg) {
        v8bf bhc[4];
#pragma unroll
        for (int ks = 0; ks < 4; ++ks) bhc[ks] = bhn[ks];
        const float sqB = sqn;
        const int tcol = tcol0 + cg * 16;

        if (cg < 15) {
            const size_t boff = (size_t)(tcol + 16) * DIM + khi * 8;
#pragma unroll
            for (int ks = 0; ks < 4; ++ks) bhn[ks] = *(const v8bf*)(xb + boff + ks * 32);
            sqn = sqv[tcol + 16];
        }

        v4f acc = {0.f, 0.f, 0.f, 0.f};
#pragma unroll
        for (int ks = 0; ks < 4; ++ks)
            acc = __builtin_amdgcn_mfma_f32_16x16x32_bf16(ah[ks], bhc[ks], acc, 0, 0, 0);

        const int tBlk = tcol >> 3;
        const bool bd0 = (tBlk != grp);
        const bool bd1 = (tBlk != grp + 256);

        float nw[4];
        bool  ic[4];
#pragma unroll
        for (int q = 0; q < 4; ++q) {
            float d2  = fmaf(-2.0f, acc[q], sqA[q] + sqB);
            float l1  = __log2f(d2);
            float t2  = fmaf(-0.25f, d2, 1.0f);
            float l2  = __log2f(t2);
            // negwinv = -exp(lg)^-1 : lg_nat = -63 ln(d2) - 62.5 ln(1-d2/4)
            float wiv = exp2f(fmaf(63.0f, l1, 62.5f * l2));
            bool incl = (d2 < 1.96f) && ((q & 1) ? bd1 : bd0);
            ic[q] = incl;
            nw[q] = incl ? -wiv : -INFINITY;
        }

        const bool uA = ic[0] | ic[1];
        const bool uB = ic[2] | ic[3];
        unsigned long long ballA = __ballot(uA);
        unsigned long long ballB = __ballot(uB);
        unsigned int subA = (unsigned int)((ballA >> (khi * 16)) & 0xFFFFull);
        unsigned int subB = (unsigned int)((ballB >> (khi * 16)) & 0xFFFFull);
        if (uA) {
            int slot = rbA + (int)cA + __popc(subA & below);
            t16[slot] = (unsigned short)tcol;
            nwp[slot] = make_float2(nw[0], nw[1]);
        }
        if (uB) {
            int slot = rbB + (int)cB + __popc(subB & below);
            t16[slot] = (unsigned short)tcol;
            nwp[slot] = make_float2(nw[2], nw[3]);
        }
        cA += (unsigned int)__popc(subA);
        cB += (unsigned int)__popc(subB);
    }

    if (rlo == 0) {
        cnt[base * 16 + chunk]       = (int)cA;
        cnt[(base + 1) * 16 + chunk] = (int)cB;
    }
}

// ---------------- kernel 2b: argmin E/w, half-pair blocks + backfill ------
// Grid 4096 blocks: block = half-pair (8 regions); wave flattens 2 regions
// (~164 entries -> ~2.6 iterations, small ragged tail). 16384 waves = 2x
// chip capacity -> scheduler backfills short blocks (fixes the R15 load-
// imbalance tail). Each lane owns one entry, 7 j-chains unrolled in regs.
// Half-blocks merge via atomicMin(u64) into pk: key (key_bits<<32)|t ==
// (key smaller)||(equal && t smaller) == reference argmax first-index.
__global__ __launch_bounds__(256, 4) void kgum(
        const int* __restrict__ cnt, const unsigned short* __restrict__ t16,
        const float2* __restrict__ nwp, unsigned long long* __restrict__ pk) {
    const int bid  = blockIdx.x;              // 0..4095
    const int p    = bid >> 1;                // pair
    const int half = bid & 1;
    const int wid  = threadIdx.x >> 6;        // 0..3
    const int lane = threadIdx.x & 63;
    const uint32_t pb0 = ((uint32_t)p * 7u) << 12;

    const int rid0 = p * 16 + half * 8 + wid * 2;
    const int n0 = cnt[rid0];
    const int n1 = cnt[rid0 + 1];
    const int tot = n0 + n1;
    const int rb0 = rid0 << 8;

    unsigned long long bA[NS], bB[NS];
#pragma unroll
    for (int j = 0; j < NS; ++j) { bA[j] = ~0ull; bB[j] = ~0ull; }

#pragma unroll 1
    for (int g = lane; g < tot; g += 64) {
        const int r = (g >= n0) ? 1 : 0;
        const int off = r ? (g - n0) : g;
        const int idx = rb0 + (r << 8) + off;
        const uint32_t t = t16[idx];
        const float2 nw  = nwp[idx];
#pragma unroll
        for (int j = 0; j < NS; ++j) {
            const uint32_t L = pb0 + ((uint32_t)j << 12) + t;
            uint32_t o0, o1;
            threefry2x32(L, L + HALF_CNT, o0, o1);
            float fA = __uint_as_float((o0 >> 9) | 0x3f800000u) - 1.0f;
            float fB = __uint_as_float((o1 >> 9) | 0x3f800000u) - 1.0f;
            float kA = __log2f(fA + 1.17549435e-38f) * nw.x;
            float kB = __log2f(fB + 1.17549435e-38f) * nw.y;
            unsigned long long pA =
                ((unsigned long long)__float_as_uint(kA) << 32) | t;
            unsigned long long pB =
                ((unsigned long long)__float_as_uint(kB) << 32) | t;
            bA[j] = pA < bA[j] ? pA : bA[j];
            bB[j] = pB < bB[j] ? pB : bB[j];
        }
    }

    // reduce across 64 lanes: u64 min per j
#pragma unroll
    for (int j = 0; j < NS; ++j) {
#pragma unroll
        for (int m = 1; m < 64; m <<= 1) {
            unsigned long long vA = __shfl_xor(bA[j], m, 64);
            unsigned long long vB = __shfl_xor(bB[j], m, 64);
            bA[j] = vA < bA[j] ? vA : bA[j];
            bB[j] = vB < bB[j] ? vB : bB[j];
        }
    }

    __shared__ unsigned long long sA[4][NS], sB[4][NS];
    if (lane == 0) {
#pragma unroll
        for (int j = 0; j < NS; ++j) { sA[wid][j] = bA[j]; sB[wid][j] = bB[j]; }
    }
    __syncthreads();
    if (threadIdx.x < 2 * NS) {
        const int r = threadIdx.x / NS, j = threadIdx.x - r * NS;
        unsigned long long v = r ? sB[0][j] : sA[0][j];
#pragma unroll
        for (int w = 1; w < 4; ++w) {
            unsigned long long v2 = r ? sB[w][j] : sA[w][j];
            v = v2 < v ? v2 : v;
        }
        atomicMin(&pk[(size_t)(p + r * 2048) * NS + j], v);
    }
}

// ---------------- kernel 3: unpack -> n_idx -------------------------------
// key bits >= 0x7F800000 (inf / untouched) <=> invalid row slot
__global__ void kextract(const unsigned long long* __restrict__ pk,
                         int* __restrict__ nidx) {
    int s = blockIdx.x * 256 + threadIdx.x;
    if (s >= NROWS * NS) return;
    unsigned long long v = pk[s];
    uint32_t kb = (uint32_t)(v >> 32);
    nidx[s] = (kb >= 0x7F800000u) ? -1 : (int)(v & 0xFFFFu);
}

// ---------------- fallback (small ws): fused sample, min-key partials -----
__global__ __launch_bounds__(256, 2) void ksample(
        const __bf16* __restrict__ xb, const float* __restrict__ sqv,
        float* __restrict__ pV, int* __restrict__ pI) {
    const int lane  = threadIdx.x & 63;
    const int chunk = (blockIdx.x << 2) + (threadIdx.x >> 6);
    const int grp   = blockIdx.y;
    const int rlo = lane & 15;
    const int khi = lane >> 4;

    const int afr = grp * 8 + (rlo >> 1) + ((rlo & 1) << 11);
    v8bf ah[4];
#pragma unroll
    for (int ks = 0; ks < 4; ++ks)
        ah[ks] = *(const v8bf*)(xb + (size_t)afr * DIM + ks * 32 + khi * 8);
    const int base = grp * 8 + khi * 2;
    float sqA[4];
    sqA[0] = sqv[base];
    sqA[1] = sqv[base + 2048];
    sqA[2] = sqv[base + 1];
    sqA[3] = sqv[base + 2049];
    const uint32_t P0 = (uint32_t)base;
    const uint32_t P1 = (uint32_t)(base + 1);

    float    bestV[4][NS];
    uint32_t bestP[4];
#pragma unroll
    for (int q = 0; q < 4; ++q) {
        bestP[q] = 0u;
#pragma unroll
        for (int j = 0; j < NS; ++j) bestV[q][j] = INFINITY;
    }
    const int tcol0 = chunk * 256 + rlo;

    v8bf bhn[4];
    float sqn;
    {
        const size_t boff = (size_t)tcol0 * DIM + khi * 8;
#pragma unroll
        for (int ks = 0; ks < 4; ++ks) bhn[ks] = *(const v8bf*)(xb + boff + ks * 32);
        sqn = sqv[tcol0];
    }

#pragma unroll 1
    for (int cg = 0; cg < 16; ++cg) {
        v8bf bhc[4];
#pragma unroll
        for (int ks = 0; ks < 4; ++ks) bhc[ks] = bhn[ks];
        const float sqB = sqn;
        const int tcol = tcol0 + cg * 16;
        if (cg < 15) {
            const size_t boff = (size_t)(tcol + 16) * DIM + khi * 8;
#pragma unroll
            for (int ks = 0; ks < 4; ++ks) bhn[ks] = *(const v8bf*)(xb + boff + ks * 32);
            sqn = sqv[tcol + 16];
        }
        v4f acc = {0.f, 0.f, 0.f, 0.f};
#pragma unroll
        for (int ks = 0; ks < 4; ++ks)
            acc = __builtin_amdgcn_mfma_f32_16x16x32_bf16(ah[ks], bhc[ks], acc, 0, 0, 0);
        const int tBlk = tcol >> 3;
        const bool bd0 = (tBlk != grp);
        const bool bd1 = (tBlk != grp + 256);
        float nw[4];
#pragma unroll
        for (int q = 0; q < 4; ++q) {
            float d2  = fmaf(-2.0f, acc[q], sqA[q] + sqB);
            float l1  = __log2f(d2);
            float t2  = fmaf(-0.25f, d2, 1.0f);
            float l2  = __log2f(t2);
            float wiv = exp2f(fmaf(63.0f, l1, 62.5f * l2));
            bool incl = (d2 < 1.96f) && ((q & 1) ? bd1 : bd0);
            nw[q] = incl ? -wiv : -INFINITY;
        }
        const uint32_t tB = (uint32_t)tcol;
#pragma unroll
        for (int j = 0; j < NS; ++j) {
            uint32_t L0 = ((P0 * 7u + (uint32_t)j) << 12) + tB;
            uint32_t L1 = ((P1 * 7u + (uint32_t)j) << 12) + tB;
            uint32_t o0, o1, o2, o3;
            threefry2x32(L0, L0 + HALF_CNT, o0, o1);
            threefry2x32(L1, L1 + HALF_CNT, o2, o3);
            float vv[4];
            vv[0] = __log2f(__uint_as_float((o0 >> 9) | 0x3f800000u) - 1.0f + 1.17549435e-38f) * nw[0];
            vv[1] = __log2f(__uint_as_float((o1 >> 9) | 0x3f800000u) - 1.0f + 1.17549435e-38f) * nw[1];
            vv[2] = __log2f(__uint_as_float((o2 >> 9) | 0x3f800000u) - 1.0f + 1.17549435e-38f) * nw[2];
            vv[3] = __log2f(__uint_as_float((o3 >> 9) | 0x3f800000u) - 1.0f + 1.17549435e-38f) * nw[3];
            const uint32_t keep = ~(0xFu << (4 * j));
            const uint32_t put  = ((uint32_t)cg) << (4 * j);
#pragma unroll
            for (int q = 0; q < 4; ++q) {
                bool lt = vv[q] < bestV[q][j];
                uint32_t np = (bestP[q] & keep) | put;
                bestV[q][j] = lt ? vv[q] : bestV[q][j];
                bestP[q]    = lt ? np : bestP[q];
            }
        }
    }
#pragma unroll
    for (int q = 0; q < 4; ++q) {
        const int a = base + (q >> 1) + ((q & 1) << 11);
#pragma unroll
        for (int j = 0; j < NS; ++j) {
            float v = bestV[q][j];
            int idx = tcol0 + (int)((bestP[q] >> (4 * j)) & 0xFu) * 16;
#pragma unroll
            for (int m = 1; m < 16; m <<= 1) {
                float v2 = __shfl_xor(v, m, 16);
                int   i2 = __shfl_xor(idx, m, 16);
                if (v2 < v || (v2 == v && i2 < idx)) { v = v2; idx = i2; }
            }
            if (rlo == 0) {
                size_t s = ((size_t)a * NS + j) * TCH + chunk;
                pV[s] = v;
                pI[s] = idx;
            }
        }
    }
}

__global__ void kcombine(const float* __restrict__ pV, const int* __restrict__ pI,
                         int* __restrict__ nidx, int nc) {
    int s = blockIdx.x * 256 + threadIdx.x;
    if (s >= NROWS * NS) return;
    float bv = INFINITY;
    int bi = 0x7FFFFFFF;
    for (int c = 0; c < nc; ++c) {
        float v = pV[(size_t)s * nc + c];
        int idx = pI[(size_t)s * nc + c];
        if (v < bv || (v == bv && idx < bi)) { bv = v; bi = idx; }
    }
    nidx[s] = (bv == INFINITY) ? -1 : bi;
}

// ---------------- kernel 4: uniform fallback for invalid rows -------------
__global__ void kfixup(int* __restrict__ nidx) {
    const int i = blockIdx.x;
    if (nidx[(size_t)i * NS] >= 0) return;   // normal case: immediate exit
    const int lane = threadIdx.x;            // 64
    for (int j = 0; j < NS; ++j) {
        float bv = -INFINITY;
        int bi = 0x7FFFFFFF;
        for (int t = lane; t < NROWS; t += 64) {
            uint32_t o0, o1;
            float g;
            if (i < 2048) {
                uint32_t L = (((uint32_t)(i * NS + j)) << 12) + (uint32_t)t;
                threefry2x32(L, L + HALF_CNT, o0, o1);
                g = gumbel_of(o0);
            } else {
                uint32_t L = (((uint32_t)((i - 2048) * NS + j)) << 12) + (uint32_t)t;
                threefry2x32(L, L + HALF_CNT, o0, o1);
                g = gumbel_of(o1);
            }
            if (g > bv) { bv = g; bi = t; }
        }
#pragma unroll
        for (int m = 1; m < 64; m <<= 1) {
            float v2 = __shfl_xor(bv, m, 64);
            int   i2 = __shfl_xor(bi, m, 64);
            if (v2 > bv || (v2 == bv && i2 < bi)) { bv = v2; bi = i2; }
        }
        if (lane == 0) nidx[i * NS + j] = bi;
    }
}

// ---------------- kernel 5: triplet losses --------------------------------
__global__ void kloss(const float* __restrict__ x, const int* __restrict__ nidx,
                      float* __restrict__ loss) {
    int s = blockIdx.x * 256 + threadIdx.x;
    if (s >= NROWS * NS) return;
    int i = s / NS, j = s - i * NS;
    int r = i & (KB - 1), blk = i >> 3;
    int po = (j < r) ? j : j + 1;
    int p = blk * KB + po;
    int n = nidx[s] & (NROWS - 1);      // defensive clamp (no-op when correct)
    const float4* A  = (const float4*)(x + (size_t)i * DIM);
    const float4* P  = (const float4*)(x + (size_t)p * DIM);
    const float4* Ng = (const float4*)(x + (size_t)n * DIM);
    float sap = 0.0f, san = 0.0f;
#pragma unroll 8
    for (int k = 0; k < DIM / 4; ++k) {
        float4 a = A[k], pv = P[k], nv = Ng[k];
        float d;
        d = a.x - pv.x + 1e-6f; sap += d * d;
        d = a.y - pv.y + 1e-6f; sap += d * d;
        d = a.z - pv.z + 1e-6f; sap += d * d;
        d = a.w - pv.w + 1e-6f; sap += d * d;
        d = a.x - nv.x + 1e-6f; san += d * d;
        d = a.y - nv.y + 1e-6f; san += d * d;
        d = a.z - nv.z + 1e-6f; san += d * d;
        d = a.w - nv.w + 1e-6f; san += d * d;
    }
    loss[s] = fmaxf(sqrtf(sap) - sqrtf(san) + 1.0f, 0.0f);
}

// ---------------- kernel 6: mean ------------------------------------------
__global__ void kreduce(const float* __restrict__ loss, float* __restrict__ out) {
    __shared__ float part[4];
    const int tid = threadIdx.x;
    float sum = 0.0f;
    for (int s = tid; s < NROWS * NS; s += 256) sum += loss[s];
#pragma unroll
    for (int m = 32; m > 0; m >>= 1) sum += __shfl_xor(sum, m, 64);
    if ((tid & 63) == 0) part[tid >> 6] = sum;
    __syncthreads();
    if (tid == 0) out[0] = (part[0] + part[1] + part[2] + part[3]) / 28672.0f;
}

extern "C" void kernel_launch(void* const* d_in, const int* in_sizes, int n_in,
                              void* d_out, int out_size, void* d_ws, size_t ws_size,
                              hipStream_t stream) {
    const float* x = (const float*)d_in[0];
    float* out = (float*)d_out;

    uint8_t* w = (uint8_t*)d_ws;
    size_t off = 0;
    auto take = [&](size_t bytes) {
        void* p = w + off;
        off = (off + bytes + 255) & ~(size_t)255;
        return p;
    };
    __bf16* xb   = (__bf16*)take((size_t)NROWS * DIM * 2);
    float*  sqv  = (float*)take((size_t)NROWS * 4);
    int*    nidx = (int*)take((size_t)NROWS * NS * 4);
    float*  loss = (float*)take((size_t)NROWS * NS * 4);
    int*    cnt  = (int*)take((size_t)NPAIR * 16 * 4);   // per-(pair,chunk)
    unsigned long long* pk = (unsigned long long*)take((size_t)NROWS * NS * 8);
    const size_t prefix = off;
    const size_t t16_b = (size_t)NPAIR * 16 * 256 * 2;   // 16.8 MB
    const size_t nwp_b = (size_t)NPAIR * 16 * 256 * 8;   // 67.1 MB
    const size_t NEED_BIG = prefix + ((t16_b + 255) & ~(size_t)255)
                          + ((nwp_b + 255) & ~(size_t)255);

    knorm<<<NROWS, 64, 0, stream>>>(x, xb, sqv);

    if (ws_size >= NEED_BIG) {
        unsigned short* t16 = (unsigned short*)take(t16_b);
        float2*         nwp = (float2*)take(nwp_b);
        hipMemsetAsync(pk, 0xFF, (size_t)NROWS * NS * 8, stream);
        kdist<<<dim3(TCH / 4, 256), 256, 0, stream>>>(xb, sqv, cnt, t16, nwp);
        kgum<<<NPAIR * 2, 256, 0, stream>>>(cnt, t16, nwp, pk);
        kextract<<<(NROWS * NS + 255) / 256, 256, 0, stream>>>(pk, nidx);
    } else {
        float* pV = (float*)take((size_t)NROWS * NS * TCH * 4);
        int*   pI = (int*)take((size_t)NROWS * NS * TCH * 4);
        ksample<<<dim3(TCH / 4, 256), 256, 0, stream>>>(xb, sqv, pV, pI);
        kcombine<<<(NROWS * NS + 255) / 256, 256, 0, stream>>>(pV, pI, nidx, TCH);
    }

    kfixup<<<NROWS, 64, 0, stream>>>(nidx);
    kloss<<<(NROWS * NS + 255) / 256, 256, 0, stream>>>(x, nidx, loss);
    kreduce<<<1, 256, 0, stream>>>(loss, out);
}

// Round 17
// 182.514 us; speedup vs baseline: 1.0940x; 1.0621x over previous
//
#include <hip/hip_runtime.h>
#include <stdint.h>

#define NROWS 4096
#define DIM   128
#define KB    8
#define NS    7            // K-1 negatives per anchor
#define TCH   16           // candidate chunks (256 cands each)
#define NPAIR 2048
#define HALF_CNT 58720256u // (4096*7*4096)/2

typedef __bf16 v8bf __attribute__((ext_vector_type(8)));
typedef float  v4f  __attribute__((ext_vector_type(4)));

// forced single-instruction rotate (v_alignbit_b32)
__device__ __forceinline__ uint32_t rotl32(uint32_t x, int r) {
    return __builtin_amdgcn_alignbit(x, x, 32 - r);
}

// JAX threefry2x32, key = [0, 42], 20 rounds. (c0,c1)=(L, L+HALF_CNT):
// o0 = bits for flat index L, o1 = bits for flat index L+HALF_CNT.
__device__ __forceinline__ void threefry2x32(uint32_t c0, uint32_t c1,
                                             uint32_t& o0, uint32_t& o1) {
    const uint32_t ks0 = 0u;
    const uint32_t ks1 = 42u;
    const uint32_t ks2 = 0x1BD11BDAu ^ ks0 ^ ks1;
    uint32_t x0 = c0 + ks0;
    uint32_t x1 = c1 + ks1;
#define TF_R(r) { x0 += x1; x1 = rotl32(x1, r); x1 ^= x0; }
    TF_R(13) TF_R(15) TF_R(26) TF_R(6)
    x0 += ks1; x1 += ks2 + 1u;
    TF_R(17) TF_R(29) TF_R(16) TF_R(24)
    x0 += ks2; x1 += ks0 + 2u;
    TF_R(13) TF_R(15) TF_R(26) TF_R(6)
    x0 += ks0; x1 += ks1 + 3u;
    TF_R(17) TF_R(29) TF_R(16) TF_R(24)
    x0 += ks1; x1 += ks2 + 4u;
    TF_R(13) TF_R(15) TF_R(26) TF_R(6)
    x0 += ks2; x1 += ks0 + 5u;
#undef TF_R
    o0 = x0; o1 = x1;
}

// gumbel = -ln(-ln(u)) (used only by the never-fires kfixup)
__device__ __forceinline__ float gumbel_of(uint32_t b) {
    float f = __uint_as_float((b >> 9) | 0x3f800000u) - 1.0f;   // [0,1)
    float u = f + 1.17549435e-38f;
    float l1 = __log2f(u);
    float inner = -0.69314718055994531f * l1;
    float l2 = __log2f(inner);
    return -0.69314718055994531f * l2;
}

// ---------------- kernel 1: normalize -> bf16 plane + sq ------------------
__global__ void knorm(const float* __restrict__ x, __bf16* __restrict__ xb,
                      float* __restrict__ sqv) {
    const int i = blockIdx.x;
    const int t = threadIdx.x;  // 64 threads, 2 elems each
    float2 v = ((const float2*)(x + (size_t)i * DIM))[t];
    float s = v.x * v.x + v.y * v.y;
#pragma unroll
    for (int m = 32; m > 0; m >>= 1) s += __shfl_xor(s, m, 64);
    float norm = sqrtf(s) + 1e-5f;
    float ox = v.x / norm, oy = v.y / norm;
    union { __bf16 b[2]; uint32_t u; } ph;
    ph.b[0] = (__bf16)ox; ph.b[1] = (__bf16)oy;
    ((uint32_t*)xb)[i * 64 + t] = ph.u;
    float s2 = ox * ox + oy * oy;
#pragma unroll
    for (int m = 32; m > 0; m >>= 1) s2 += __shfl_xor(s2, m, 64);
    if (t == 0) sqv[i] = s2;
}

// ---------------- kernel 2a: MFMA dists -> compacted lists (negwinv) ------
// (R14/R16 config: 256-thread blocks, 4 chunks/block — measured best)
__global__ __launch_bounds__(256, 4) void kdist(
        const __bf16* __restrict__ xb, const float* __restrict__ sqv,
        int* __restrict__ cnt, unsigned short* __restrict__ t16,
        float2* __restrict__ nwp) {
    const int lane  = threadIdx.x & 63;
    const int chunk = (blockIdx.x << 2) + (threadIdx.x >> 6);   // 0..15
    const int grp   = blockIdx.y;   // 0..255
    const int rlo = lane & 15;
    const int khi = lane >> 4;
    const unsigned int below = (1u << rlo) - 1u;

    const int afr = grp * 8 + (rlo >> 1) + ((rlo & 1) << 11);
    v8bf ah[4];
#pragma unroll
    for (int ks = 0; ks < 4; ++ks)
        ah[ks] = *(const v8bf*)(xb + (size_t)afr * DIM + ks * 32 + khi * 8);

    const int base = grp * 8 + khi * 2;   // pairA = base, pairB = base+1
    float sqA[4];
    sqA[0] = sqv[base];
    sqA[1] = sqv[base + 2048];
    sqA[2] = sqv[base + 1];
    sqA[3] = sqv[base + 2049];

    const int rbA = ((base)     * 16 + chunk) << 8;
    const int rbB = ((base + 1) * 16 + chunk) << 8;
    unsigned int cA = 0, cB = 0;          // uniform within 16-group

    const int tcol0 = chunk * 256 + rlo;

    v8bf bhn[4];
    float sqn;
    {
        const size_t boff = (size_t)tcol0 * DIM + khi * 8;
#pragma unroll
        for (int ks = 0; ks < 4; ++ks) bhn[ks] = *(const v8bf*)(xb + boff + ks * 32);
        sqn = sqv[tcol0];
    }

#pragma unroll 1
    for (int cg = 0; cg < 16; ++cg) {
        v8bf bhc[4];
#pragma unroll
        for (int ks = 0; ks < 4; ++ks) bhc[ks] = bhn[ks];
        const float sqB = sqn;
        const int tcol = tcol0 + cg * 16;

        if (cg < 15) {
            const size_t boff = (size_t)(tcol + 16) * DIM + khi * 8;
#pragma unroll
            for (int ks = 0; ks < 4; ++ks) bhn[ks] = *(const v8bf*)(xb + boff + ks * 32);
            sqn = sqv[tcol + 16];
        }

        v4f acc = {0.f, 0.f, 0.f, 0.f};
#pragma unroll
        for (int ks = 0; ks < 4; ++ks)
            acc = __builtin_amdgcn_mfma_f32_16x16x32_bf16(ah[ks], bhc[ks], acc, 0, 0, 0);

        const int tBlk = tcol >> 3;
        const bool bd0 = (tBlk != grp);
        const bool bd1 = (tBlk != grp + 256);

        float nw[4];
        bool  ic[4];
#pragma unroll
        for (int q = 0; q < 4; ++q) {
            float d2  = fmaf(-2.0f, acc[q], sqA[q] + sqB);
            float l1  = __log2f(d2);
            float t2  = fmaf(-0.25f, d2, 1.0f);
            float l2  = __log2f(t2);
            // negwinv = -exp(lg)^-1 : lg_nat = -63 ln(d2) - 62.5 ln(1-d2/4)
            float wiv = exp2f(fmaf(63.0f, l1, 62.5f * l2));
            bool incl = (d2 < 1.96f) && ((q & 1) ? bd1 : bd0);
            ic[q] = incl;
            nw[q] = incl ? -wiv : -INFINITY;
        }

        const bool uA = ic[0] | ic[1];
        const bool uB = ic[2] | ic[3];
        unsigned long long ballA = __ballot(uA);
        unsigned long long ballB = __ballot(uB);
        unsigned int subA = (unsigned int)((ballA >> (khi * 16)) & 0xFFFFull);
        unsigned int subB = (unsigned int)((ballB >> (khi * 16)) & 0xFFFFull);
        if (uA) {
            int slot = rbA + (int)cA + __popc(subA & below);
            t16[slot] = (unsigned short)tcol;
            nwp[slot] = make_float2(nw[0], nw[1]);
        }
        if (uB) {
            int slot = rbB + (int)cB + __popc(subB & below);
            t16[slot] = (unsigned short)tcol;
            nwp[slot] = make_float2(nw[2], nw[3]);
        }
        cA += (unsigned int)__popc(subA);
        cB += (unsigned int)__popc(subB);
    }

    if (rlo == 0) {
        cnt[base * 16 + chunk]       = (int)cA;
        cnt[(base + 1) * 16 + chunk] = (int)cB;
    }
}

// ---------------- kernel 2b: argmin E/w, flattened 4-region scan ----------
// (R15-measured best: 104.2 us.) Block = pair (2048 x 256). Wave w owns
// regions 4w..4w+3 FLATTENED into one index space so ragged tails don't
// idle lanes. Each lane owns one entry, 7 j-chains unrolled in registers.
// Block LDS-reduce writes nidx directly. u64 key (key_bits<<32)|t ==
// (key smaller)||(equal && t smaller) == reference argmax first-index.
__global__ __launch_bounds__(256, 4) void kgum(
        const int* __restrict__ cnt, const unsigned short* __restrict__ t16,
        const float2* __restrict__ nwp, int* __restrict__ nidx) {
    const int p    = blockIdx.x;              // pair
    const int wid  = threadIdx.x >> 6;        // 0..3
    const int lane = threadIdx.x & 63;
    const uint32_t pb0 = ((uint32_t)p * 7u) << 12;

    const int rid0 = p * 16 + wid * 4;
    const int n0 = cnt[rid0];
    const int n1 = cnt[rid0 + 1];
    const int n2 = cnt[rid0 + 2];
    const int n3 = cnt[rid0 + 3];
    const int s1 = n0 + n1;
    const int s2 = s1 + n2;
    const int tot = s2 + n3;
    const int rb0 = rid0 << 8;

    unsigned long long bA[NS], bB[NS];
#pragma unroll
    for (int j = 0; j < NS; ++j) { bA[j] = ~0ull; bB[j] = ~0ull; }

#pragma unroll 1
    for (int g = lane; g < tot; g += 64) {
        int r, off;
        if (g < n0)      { r = 0; off = g; }
        else if (g < s1) { r = 1; off = g - n0; }
        else if (g < s2) { r = 2; off = g - s1; }
        else             { r = 3; off = g - s2; }
        const int idx = rb0 + (r << 8) + off;
        const uint32_t t = t16[idx];
        const float2 nw  = nwp[idx];
#pragma unroll
        for (int j = 0; j < NS; ++j) {
            const uint32_t L = pb0 + ((uint32_t)j << 12) + t;
            uint32_t o0, o1;
            threefry2x32(L, L + HALF_CNT, o0, o1);
            float fA = __uint_as_float((o0 >> 9) | 0x3f800000u) - 1.0f;
            float fB = __uint_as_float((o1 >> 9) | 0x3f800000u) - 1.0f;
            float kA = __log2f(fA + 1.17549435e-38f) * nw.x;
            float kB = __log2f(fB + 1.17549435e-38f) * nw.y;
            unsigned long long pA =
                ((unsigned long long)__float_as_uint(kA) << 32) | t;
            unsigned long long pB =
                ((unsigned long long)__float_as_uint(kB) << 32) | t;
            bA[j] = pA < bA[j] ? pA : bA[j];
            bB[j] = pB < bB[j] ? pB : bB[j];
        }
    }

    // reduce across 64 lanes: u64 min per j
#pragma unroll
    for (int j = 0; j < NS; ++j) {
#pragma unroll
        for (int m = 1; m < 64; m <<= 1) {
            unsigned long long vA = __shfl_xor(bA[j], m, 64);
            unsigned long long vB = __shfl_xor(bB[j], m, 64);
            bA[j] = vA < bA[j] ? vA : bA[j];
            bB[j] = vB < bB[j] ? vB : bB[j];
        }
    }

    __shared__ unsigned long long sA[4][NS], sB[4][NS];
    if (lane == 0) {
#pragma unroll
        for (int j = 0; j < NS; ++j) { sA[wid][j] = bA[j]; sB[wid][j] = bB[j]; }
    }
    __syncthreads();
    if (threadIdx.x < 2 * NS) {
        const int r = threadIdx.x / NS, j = threadIdx.x - r * NS;
        unsigned long long v = r ? sB[0][j] : sA[0][j];
#pragma unroll
        for (int w = 1; w < 4; ++w) {
            unsigned long long v2 = r ? sB[w][j] : sA[w][j];
            v = v2 < v ? v2 : v;
        }
        uint32_t kb = (uint32_t)(v >> 32);
        nidx[(p + r * 2048) * NS + j] = (kb >= 0x7F800000u) ? -1
                                                            : (int)(v & 0xFFFFu);
    }
}

// ---------------- fallback (small ws): fused sample, min-key partials -----
__global__ __launch_bounds__(256, 2) void ksample(
        const __bf16* __restrict__ xb, const float* __restrict__ sqv,
        float* __restrict__ pV, int* __restrict__ pI) {
    const int lane  = threadIdx.x & 63;
    const int chunk = (blockIdx.x << 2) + (threadIdx.x >> 6);
    const int grp   = blockIdx.y;
    const int rlo = lane & 15;
    const int khi = lane >> 4;

    const int afr = grp * 8 + (rlo >> 1) + ((rlo & 1) << 11);
    v8bf ah[4];
#pragma unroll
    for (int ks = 0; ks < 4; ++ks)
        ah[ks] = *(const v8bf*)(xb + (size_t)afr * DIM + ks * 32 + khi * 8);
    const int base = grp * 8 + khi * 2;
    float sqA[4];
    sqA[0] = sqv[base];
    sqA[1] = sqv[base + 2048];
    sqA[2] = sqv[base + 1];
    sqA[3] = sqv[base + 2049];
    const uint32_t P0 = (uint32_t)base;
    const uint32_t P1 = (uint32_t)(base + 1);

    float    bestV[4][NS];
    uint32_t bestP[4];
#pragma unroll
    for (int q = 0; q < 4; ++q) {
        bestP[q] = 0u;
#pragma unroll
        for (int j = 0; j < NS; ++j) bestV[q][j] = INFINITY;
    }
    const int tcol0 = chunk * 256 + rlo;

    v8bf bhn[4];
    float sqn;
    {
        const size_t boff = (size_t)tcol0 * DIM + khi * 8;
#pragma unroll
        for (int ks = 0; ks < 4; ++ks) bhn[ks] = *(const v8bf*)(xb + boff + ks * 32);
        sqn = sqv[tcol0];
    }

#pragma unroll 1
    for (int cg = 0; cg < 16; ++cg) {
        v8bf bhc[4];
#pragma unroll
        for (int ks = 0; ks < 4; ++ks) bhc[ks] = bhn[ks];
        const float sqB = sqn;
        const int tcol = tcol0 + cg * 16;
        if (cg < 15) {
            const size_t boff = (size_t)(tcol + 16) * DIM + khi * 8;
#pragma unroll
            for (int ks = 0; ks < 4; ++ks) bhn[ks] = *(const v8bf*)(xb + boff + ks * 32);
            sqn = sqv[tcol + 16];
        }
        v4f acc = {0.f, 0.f, 0.f, 0.f};
#pragma unroll
        for (int ks = 0; ks < 4; ++ks)
            acc = __builtin_amdgcn_mfma_f32_16x16x32_bf16(ah[ks], bhc[ks], acc, 0, 0, 0);
        const int tBlk = tcol >> 3;
        const bool bd0 = (tBlk != grp);
        const bool bd1 = (tBlk != grp + 256);
        float nw[4];
#pragma unroll
        for (int q = 0; q < 4; ++q) {
            float d2  = fmaf(-2.0f, acc[q], sqA[q] + sqB);
            float l1  = __log2f(d2);
            float t2  = fmaf(-0.25f, d2, 1.0f);
            float l2  = __log2f(t2);
            float wiv = exp2f(fmaf(63.0f, l1, 62.5f * l2));
            bool incl = (d2 < 1.96f) && ((q & 1) ? bd1 : bd0);
            nw[q] = incl ? -wiv : -INFINITY;
        }
        const uint32_t tB = (uint32_t)tcol;
#pragma unroll
        for (int j = 0; j < NS; ++j) {
            uint32_t L0 = ((P0 * 7u + (uint32_t)j) << 12) + tB;
            uint32_t L1 = ((P1 * 7u + (uint32_t)j) << 12) + tB;
            uint32_t o0, o1, o2, o3;
            threefry2x32(L0, L0 + HALF_CNT, o0, o1);
            threefry2x32(L1, L1 + HALF_CNT, o2, o3);
            float vv[4];
            vv[0] = __log2f(__uint_as_float((o0 >> 9) | 0x3f800000u) - 1.0f + 1.17549435e-38f) * nw[0];
            vv[1] = __log2f(__uint_as_float((o1 >> 9) | 0x3f800000u) - 1.0f + 1.17549435e-38f) * nw[1];
            vv[2] = __log2f(__uint_as_float((o2 >> 9) | 0x3f800000u) - 1.0f + 1.17549435e-38f) * nw[2];
            vv[3] = __log2f(__uint_as_float((o3 >> 9) | 0x3f800000u) - 1.0f + 1.17549435e-38f) * nw[3];
            const uint32_t keep = ~(0xFu << (4 * j));
            const uint32_t put  = ((uint32_t)cg) << (4 * j);
#pragma unroll
            for (int q = 0; q < 4; ++q) {
                bool lt = vv[q] < bestV[q][j];
                uint32_t np = (bestP[q] & keep) | put;
                bestV[q][j] = lt ? vv[q] : bestV[q][j];
                bestP[q]    = lt ? np : bestP[q];
            }
        }
    }
#pragma unroll
    for (int q = 0; q < 4; ++q) {
        const int a = base + (q >> 1) + ((q & 1) << 11);
#pragma unroll
        for (int j = 0; j < NS; ++j) {
            float v = bestV[q][j];
            int idx = tcol0 + (int)((bestP[q] >> (4 * j)) & 0xFu) * 16;
#pragma unroll
            for (int m = 1; m < 16; m <<= 1) {
                float v2 = __shfl_xor(v, m, 16);
                int   i2 = __shfl_xor(idx, m, 16);
                if (v2 < v || (v2 == v && i2 < idx)) { v = v2; idx = i2; }
            }
            if (rlo == 0) {
                size_t s = ((size_t)a * NS + j) * TCH + chunk;
                pV[s] = v;
                pI[s] = idx;
            }
        }
    }
}

__global__ void kcombine(const float* __restrict__ pV, const int* __restrict__ pI,
                         int* __restrict__ nidx, int nc) {
    int s = blockIdx.x * 256 + threadIdx.x;
    if (s >= NROWS * NS) return;
    float bv = INFINITY;
    int bi = 0x7FFFFFFF;
    for (int c = 0; c < nc; ++c) {
        float v = pV[(size_t)s * nc + c];
        int idx = pI[(size_t)s * nc + c];
        if (v < bv || (v == bv && idx < bi)) { bv = v; bi = idx; }
    }
    nidx[s] = (bv == INFINITY) ? -1 : bi;
}

// ---------------- kernel 4: uniform fallback for invalid rows -------------
__global__ void kfixup(int* __restrict__ nidx) {
    const int i = blockIdx.x;
    if (nidx[(size_t)i * NS] >= 0) return;   // normal case: immediate exit
    const int lane = threadIdx.x;            // 64
    for (int j = 0; j < NS; ++j) {
        float bv = -INFINITY;
        int bi = 0x7FFFFFFF;
        for (int t = lane; t < NROWS; t += 64) {
            uint32_t o0, o1;
            float g;
            if (i < 2048) {
                uint32_t L = (((uint32_t)(i * NS + j)) << 12) + (uint32_t)t;
                threefry2x32(L, L + HALF_CNT, o0, o1);
                g = gumbel_of(o0);
            } else {
                uint32_t L = (((uint32_t)((i - 2048) * NS + j)) << 12) + (uint32_t)t;
                threefry2x32(L, L + HALF_CNT, o0, o1);
                g = gumbel_of(o1);
            }
            if (g > bv) { bv = g; bi = t; }
        }
#pragma unroll
        for (int m = 1; m < 64; m <<= 1) {
            float v2 = __shfl_xor(bv, m, 64);
            int   i2 = __shfl_xor(bi, m, 64);
            if (v2 > bv || (v2 == bv && i2 < bi)) { bv = v2; bi = i2; }
        }
        if (lane == 0) nidx[i * NS + j] = bi;
    }
}

// ---------------- kernel 5: triplet losses --------------------------------
__global__ void kloss(const float* __restrict__ x, const int* __restrict__ nidx,
                      float* __restrict__ loss) {
    int s = blockIdx.x * 256 + threadIdx.x;
    if (s >= NROWS * NS) return;
    int i = s / NS, j = s - i * NS;
    int r = i & (KB - 1), blk = i >> 3;
    int po = (j < r) ? j : j + 1;
    int p = blk * KB + po;
    int n = nidx[s] & (NROWS - 1);      // defensive clamp (no-op when correct)
    const float4* A  = (const float4*)(x + (size_t)i * DIM);
    const float4* P  = (const float4*)(x + (size_t)p * DIM);
    const float4* Ng = (const float4*)(x + (size_t)n * DIM);
    float sap = 0.0f, san = 0.0f;
#pragma unroll 8
    for (int k = 0; k < DIM / 4; ++k) {
        float4 a = A[k], pv = P[k], nv = Ng[k];
        float d;
        d = a.x - pv.x + 1e-6f; sap += d * d;
        d = a.y - pv.y + 1e-6f; sap += d * d;
        d = a.z - pv.z + 1e-6f; sap += d * d;
        d = a.w - pv.w + 1e-6f; sap += d * d;
        d = a.x - nv.x + 1e-6f; san += d * d;
        d = a.y - nv.y + 1e-6f; san += d * d;
        d = a.z - nv.z + 1e-6f; san += d * d;
        d = a.w - nv.w + 1e-6f; san += d * d;
    }
    loss[s] = fmaxf(sqrtf(sap) - sqrtf(san) + 1.0f, 0.0f);
}

// ---------------- kernel 6: mean ------------------------------------------
__global__ void kreduce(const float* __restrict__ loss, float* __restrict__ out) {
    __shared__ float part[4];
    const int tid = threadIdx.x;
    float sum = 0.0f;
    for (int s = tid; s < NROWS * NS; s += 256) sum += loss[s];
#pragma unroll
    for (int m = 32; m > 0; m >>= 1) sum += __shfl_xor(sum, m, 64);
    if ((tid & 63) == 0) part[tid >> 6] = sum;
    __syncthreads();
    if (tid == 0) out[0] = (part[0] + part[1] + part[2] + part[3]) / 28672.0f;
}

extern "C" void kernel_launch(void* const* d_in, const int* in_sizes, int n_in,
                              void* d_out, int out_size, void* d_ws, size_t ws_size,
                              hipStream_t stream) {
    const float* x = (const float*)d_in[0];
    float* out = (float*)d_out;

    uint8_t* w = (uint8_t*)d_ws;
    size_t off = 0;
    auto take = [&](size_t bytes) {
        void* p = w + off;
        off = (off + bytes + 255) & ~(size_t)255;
        return p;
    };
    __bf16* xb   = (__bf16*)take((size_t)NROWS * DIM * 2);
    float*  sqv  = (float*)take((size_t)NROWS * 4);
    int*    nidx = (int*)take((size_t)NROWS * NS * 4);
    float*  loss = (float*)take((size_t)NROWS * NS * 4);
    int*    cnt  = (int*)take((size_t)NPAIR * 16 * 4);   // per-(pair,chunk)
    const size_t prefix = off;
    const size_t t16_b = (size_t)NPAIR * 16 * 256 * 2;   // 16.8 MB
    const size_t nwp_b = (size_t)NPAIR * 16 * 256 * 8;   // 67.1 MB
    const size_t NEED_BIG = prefix + ((t16_b + 255) & ~(size_t)255)
                          + ((nwp_b + 255) & ~(size_t)255);

    knorm<<<NROWS, 64, 0, stream>>>(x, xb, sqv);

    if (ws_size >= NEED_BIG) {
        unsigned short* t16 = (unsigned short*)take(t16_b);
        float2*         nwp = (float2*)take(nwp_b);
        kdist<<<dim3(TCH / 4, 256), 256, 0, stream>>>(xb, sqv, cnt, t16, nwp);
        kgum<<<NPAIR, 256, 0, stream>>>(cnt, t16, nwp, nidx);
    } else {
        float* pV = (float*)take((size_t)NROWS * NS * TCH * 4);
        int*   pI = (int*)take((size_t)NROWS * NS * TCH * 4);
        ksample<<<dim3(TCH / 4, 256), 256, 0, stream>>>(xb, sqv, pV, pI);
        kcombine<<<(NROWS * NS + 255) / 256, 256, 0, stream>>>(pV, pI, nidx, TCH);
    }

    kfixup<<<NROWS, 64, 0, stream>>>(nidx);
    kloss<<<(NROWS * NS + 255) / 256, 256, 0, stream>>>(x, nidx, loss);
    kreduce<<<1, 256, 0, stream>>>(loss, out);
}